// Round 7
// baseline (242.349 us; speedup 1.0000x reference)
//
#include <hip/hip_runtime.h>
#include <hip/hip_bf16.h>
#include <hip/hip_cooperative_groups.h>

namespace cg = cooperative_groups;

#define B_ 4
#define T_ 800
#define U_ 150
#define D_ 512
#define H_ 256
#define PADH2 132   // 132 % 32 == 4 -> worst LDS aliasing 2-way (free)
#define GRID_ 512

static constexpr float ARG_SCALE = 2.8853900817779268f; // 2/ln2: tanh(x)=1-2/(1+2^(c*x))
static constexpr float LOG2E_F   = 1.4426950408889634f;

typedef __attribute__((ext_vector_type(8))) short bf16x8;
typedef __attribute__((ext_vector_type(4))) float f32x4;

extern "C" __device__ float __ocml_exp2_f32(float);

__device__ __forceinline__ float fast_exp2(float x) {
#if __has_builtin(__builtin_amdgcn_exp2f)
    return __builtin_amdgcn_exp2f(x);
#else
    return __ocml_exp2_f32(x);
#endif
}
__device__ __forceinline__ float fast_rcp(float x) {
#if __has_builtin(__builtin_amdgcn_rcpf)
    return __builtin_amdgcn_rcpf(x);
#else
    return 1.0f / x;
#endif
}

// round-to-nearest-even fp32 -> bf16 hi, residual lo
__device__ __forceinline__ void bf16split(float x, unsigned short& hi, unsigned short& lo) {
    unsigned u = __builtin_bit_cast(unsigned, x);
    unsigned r = (u + 0x7FFFu + ((u >> 16) & 1u)) >> 16;
    hi = (unsigned short)r;
    float fh = __builtin_bit_cast(float, r << 16);
    float d = x - fh;
    unsigned u2 = __builtin_bit_cast(unsigned, d);
    unsigned r2 = (u2 + 0x7FFFu + ((u2 >> 16) & 1u)) >> 16;
    lo = (unsigned short)r2;
}

// ---------------------------------------------------------------------------
// One cooperative kernel, 4 phases separated by grid syncs.
// Phase 0: convert c*W -> frag-ordered bf16 hi/lo; convert enc/dec rows ->
//          frag-ordered bf16 hi/lo A-chunks (16 rows each).
// Phase 1: LDS-free MFMA projection (hi/lo 3-pass) + exp2 -> Ee/Ed.
// Phase 2: score partials via 1-rcp-per-4h rational form -> sc0/sc1.
// Phase 3: row softmax of -2*(sc0+sc1) -> out.
// ---------------------------------------------------------------------------
__global__ __launch_bounds__(256, 2) void fused_kernel(
    const float* __restrict__ enc, const float* __restrict__ dec,
    const float* __restrict__ W_enc, const float* __restrict__ b_enc,
    const float* __restrict__ W_dec, const float* __restrict__ b_dec,
    const float* __restrict__ w_score,
    float* __restrict__ Ee, float* __restrict__ Ed,
    float* __restrict__ sc0, float* __restrict__ sc1,
    unsigned short* __restrict__ WtEh, unsigned short* __restrict__ WtEl,
    unsigned short* __restrict__ WtDh, unsigned short* __restrict__ WtDl,
    unsigned short* __restrict__ AEh, unsigned short* __restrict__ AEl,
    unsigned short* __restrict__ ADh, unsigned short* __restrict__ ADl,
    float* __restrict__ out)
{
    const int tid = threadIdx.x;
    const int blk = blockIdx.x;
    const int nthreads = gridDim.x * 256;
    const int gtid = blk * 256 + tid;

    __shared__ float smem[2][2][32][PADH2];   // 67584 B -> 2 blocks/CU

    // ================= PHASE 0a: W conversion (2*512*256 elems) ============
    for (int i = gtid; i < 2 * D_ * H_; i += nthreads) {
        const int which = i >> 17;
        const int r = i & (D_ * H_ - 1);
        const int e = r >> 8, h = r & 255;
        const float x = ARG_SCALE * (which ? W_dec[r] : W_enc[r]);
        unsigned short hi, lo; bf16split(x, hi, lo);
        const int s = e >> 5, q = (e >> 3) & 3, j = e & 7;
        const int g = h >> 4, rr = h & 15, l = q * 16 + rr;
        const size_t idx = (size_t)(s * 16 + g) * 512 + l * 8 + j;
        if (which) { WtDh[idx] = hi; WtDl[idx] = lo; }
        else       { WtEh[idx] = hi; WtEl[idx] = lo; }
    }
    // ================= PHASE 0b: A conversion (238 chunks x 16 x 64 x 8) ===
    for (int u = gtid; u < 238 * 1024; u += nthreads) {
        const int c = u >> 10;
        const int rem = u & 1023;
        const int s = rem >> 6, l = rem & 63;
        const float* in; unsigned short *oh, *ol; int cl, rmax;
        if (c < 200) { in = enc; oh = AEh; ol = AEl; cl = c;       rmax = 3199; }
        else         { in = dec; oh = ADh; ol = ADl; cl = c - 200; rmax = 599; }
        int row = cl * 16 + (l & 15); if (row > rmax) row = rmax;
        const int e0 = s * 32 + (l >> 4) * 8;
        const float4 f0 = ((const float4*)(in + (size_t)row * D_ + e0))[0];
        const float4 f1 = ((const float4*)(in + (size_t)row * D_ + e0))[1];
        const float v[8] = {f0.x, f0.y, f0.z, f0.w, f1.x, f1.y, f1.z, f1.w};
        bf16x8 ah, al;
        #pragma unroll
        for (int j = 0; j < 8; ++j) {
            unsigned short hi, lo; bf16split(v[j], hi, lo);
            ah[j] = (short)hi; al[j] = (short)lo;
        }
        const size_t di = ((size_t)(cl * 16 + s) * 64 + l) * 8;
        *(bf16x8*)&oh[di] = ah;
        *(bf16x8*)&ol[di] = al;
    }

    cg::this_grid().sync();

    // ================= PHASE 1: LDS-free MFMA projection + exp2 =============
    {
        const int lane = tid & 63, w = tid >> 6;
        const int q = lane >> 4, r15 = lane & 15;
        for (int u = blk; u < 952; u += gridDim.x) {
            const unsigned short *Ah_, *Al_, *Wh_, *Wl_; const float* bias;
            float* outp; int cl, hq, rmax;
            if (u < 800) { cl = u >> 2; hq = u & 3; Ah_ = AEh; Al_ = AEl;
                           Wh_ = WtEh; Wl_ = WtEl; bias = b_enc; outp = Ee; rmax = 3199; }
            else { const int u2 = u - 800; cl = u2 >> 2; hq = u2 & 3; Ah_ = ADh; Al_ = ADl;
                   Wh_ = WtDh; Wl_ = WtDl; bias = b_dec; outp = Ed; rmax = 599; }
            const int g = 4 * hq + w;
            const int row0 = cl * 16;
            const unsigned short* ap_h = Ah_ + ((size_t)(cl * 16) * 64 + lane) * 8;
            const unsigned short* ap_l = Al_ + ((size_t)(cl * 16) * 64 + lane) * 8;
            const unsigned short* bp_h = Wh_ + (size_t)g * 512 + lane * 8;
            const unsigned short* bp_l = Wl_ + (size_t)g * 512 + lane * 8;
            f32x4 acc = {0.f, 0.f, 0.f, 0.f};
            #pragma unroll 4
            for (int s = 0; s < 16; ++s) {
                const bf16x8 ah = *(const bf16x8*)(ap_h + (size_t)s * 512);
                const bf16x8 al = *(const bf16x8*)(ap_l + (size_t)s * 512);
                const bf16x8 bh = *(const bf16x8*)(bp_h + (size_t)s * 8192);
                const bf16x8 bl = *(const bf16x8*)(bp_l + (size_t)s * 8192);
                acc = __builtin_amdgcn_mfma_f32_16x16x32_bf16(ah, bh, acc, 0, 0, 0);
                acc = __builtin_amdgcn_mfma_f32_16x16x32_bf16(ah, bl, acc, 0, 0, 0);
                acc = __builtin_amdgcn_mfma_f32_16x16x32_bf16(al, bh, acc, 0, 0, 0);
            }
            const int h = g * 16 + r15;
            const float bv = bias[h];
            #pragma unroll
            for (int reg = 0; reg < 4; ++reg) {
                const int trow = row0 + 4 * q + reg;
                if (trow <= rmax)
                    outp[(size_t)trow * H_ + h] = fast_exp2(fmaf(ARG_SCALE, bv, acc[reg]));
            }
        }
    }

    cg::this_grid().sync();

    // ================= PHASE 2: score partials ==============================
    {
        const int sub = tid >> 7, t128 = tid & 127;
        float (*eld)[PADH2] = smem[sub][0];
        float (*dld)[PADH2] = smem[sub][1];
        const int hs = sub, hoff = hs * 128;
        const float* wp = w_score + hoff;
        float* sout = hs ? sc1 : sc0;

        for (int u2 = blk; u2 < 500; u2 += gridDim.x) {
            const int ut = u2 % 5, tt = (u2 / 5) % 25, b = u2 / 125;
            const int t0 = tt * 32, u0 = ut * 32;

            #pragma unroll
            for (int k = 0; k < 8; ++k) {
                const int idx = t128 + 128 * k;
                const int row = idx >> 5, f4 = idx & 31;
                *(float4*)&eld[row][4 * f4] =
                    *(const float4*)(Ee + (size_t)(b * T_ + t0 + row) * H_ + hoff + 4 * f4);
                int du = u0 + row; if (du > U_ - 1) du = U_ - 1;
                *(float4*)&dld[row][4 * f4] =
                    *(const float4*)(Ed + (size_t)(b * U_ + du) * H_ + hoff + 4 * f4);
            }
            __syncthreads();

            const int tx = t128 & 15, ty = t128 >> 4;    // ty 0..7
            const float* e0 = &eld[4 * ty + 0][0];
            const float* e1 = &eld[4 * ty + 1][0];
            const float* e2 = &eld[4 * ty + 2][0];
            const float* e3 = &eld[4 * ty + 3][0];
            const float* d0 = &dld[tx][0];
            const float* d1 = &dld[tx + 16][0];

            float a00 = 0.f, a01 = 0.f, a10 = 0.f, a11 = 0.f;
            float a20 = 0.f, a21 = 0.f, a30 = 0.f, a31 = 0.f;

#define SQUAD(EV, DV, A) { \
    float q0 = fmaf(EV.x, DV.x, 1.f); \
    float q1 = fmaf(EV.y, DV.y, 1.f); \
    float q2 = fmaf(EV.z, DV.z, 1.f); \
    float q3 = fmaf(EV.w, DV.w, 1.f); \
    float Dab = q0 * q1, Dcd = q2 * q3; \
    float Nab = fmaf(w.x, q1, w.y * q0); \
    float Ncd = fmaf(w.z, q3, w.w * q2); \
    float N = fmaf(Nab, Dcd, Ncd * Dab); \
    A = fmaf(N, fast_rcp(Dab * Dcd), A); }

            #pragma unroll 4
            for (int h4 = 0; h4 < 32; ++h4) {
                const float4 w  = ((const float4*)wp)[h4];
                const float4 ea = *(const float4*)(e0 + 4 * h4);
                const float4 eb = *(const float4*)(e1 + 4 * h4);
                const float4 ec = *(const float4*)(e2 + 4 * h4);
                const float4 ed = *(const float4*)(e3 + 4 * h4);
                const float4 da = *(const float4*)(d0 + 4 * h4);
                const float4 db = *(const float4*)(d1 + 4 * h4);
                SQUAD(ea, da, a00) SQUAD(ea, db, a01)
                SQUAD(eb, da, a10) SQUAD(eb, db, a11)
                SQUAD(ec, da, a20) SQUAD(ec, db, a21)
                SQUAD(ed, da, a30) SQUAD(ed, db, a31)
            }
#undef SQUAD

            const float s0[4] = {a00, a10, a20, a30};
            const float s1[4] = {a01, a11, a21, a31};
            const int ua = u0 + tx, ub = ua + 16;
            #pragma unroll
            for (int j = 0; j < 4; ++j) {
                const int t = t0 + 4 * ty + j;
                const size_t base = (size_t)(b * T_ + t) * U_;
                sout[base + ua] = s0[j];
                if (ub < U_) sout[base + ub] = s1[j];
            }
            __syncthreads();
        }
    }

    cg::this_grid().sync();

    // ================= PHASE 3: softmax =====================================
    {
        const int wave = tid >> 6, lane = tid & 63;
        for (int unit = blk; unit < 800; unit += gridDim.x) {
            const int row = unit * 4 + wave;
            const size_t base = (size_t)row * U_;

            float z0 = -2.f * (sc0[base + lane]      + sc1[base + lane]);
            float z1 = -2.f * (sc0[base + lane + 64] + sc1[base + lane + 64]);
            const bool v2 = (lane + 128) < U_;
            float z2 = v2 ? -2.f * (sc0[base + lane + 128] + sc1[base + lane + 128])
                          : -INFINITY;

            float m = fmaxf(fmaxf(z0, z1), z2);
            #pragma unroll
            for (int off = 32; off > 0; off >>= 1) m = fmaxf(m, __shfl_xor(m, off));

            float p0 = fast_exp2((z0 - m) * LOG2E_F);
            float p1 = fast_exp2((z1 - m) * LOG2E_F);
            float p2 = v2 ? fast_exp2((z2 - m) * LOG2E_F) : 0.f;

            float s = p0 + p1 + p2;
            #pragma unroll
            for (int off = 32; off > 0; off >>= 1) s += __shfl_xor(s, off);

            const float inv = 1.0f / s;
            out[base + lane]      = p0 * inv;
            out[base + lane + 64] = p1 * inv;
            if (v2) out[base + lane + 128] = p2 * inv;
        }
    }
}

// ---------------------------------------------------------------------------
extern "C" void kernel_launch(void* const* d_in, const int* in_sizes, int n_in,
                              void* d_out, int out_size, void* d_ws, size_t ws_size,
                              hipStream_t stream) {
    const float* enc     = (const float*)d_in[0];
    const float* dec     = (const float*)d_in[1];
    const float* W_enc   = (const float*)d_in[2];
    const float* b_enc   = (const float*)d_in[3];
    const float* W_dec   = (const float*)d_in[4];
    const float* b_dec   = (const float*)d_in[5];
    const float* w_score = (const float*)d_in[6];
    // d_in[7] = b_score: cancels in softmax, unused.

    float* ws  = (float*)d_ws;
    float* Ee  = ws;                    // [3200,256]
    float* Ed  = Ee + 819200;           // [600,256]
    float* sc0 = Ed + 153600;           // [3200,150]
    float* sc1 = sc0 + 480000;          // [3200,150]
    unsigned short* WtEh = (unsigned short*)(sc1 + 480000);
    unsigned short* WtEl = WtEh + 131072;
    unsigned short* WtDh = WtEl + 131072;
    unsigned short* WtDl = WtDh + 131072;
    unsigned short* AEh  = WtDl + 131072;   // 200*16*64*8 = 1638400
    unsigned short* AEl  = AEh + 1638400;
    unsigned short* ADh  = AEl + 1638400;   // 38*16*64*8 = 311296
    unsigned short* ADl  = ADh + 311296;
    float* out = (float*)d_out;

    void* args[] = {
        (void*)&enc, (void*)&dec, (void*)&W_enc, (void*)&b_enc,
        (void*)&W_dec, (void*)&b_dec, (void*)&w_score,
        (void*)&Ee, (void*)&Ed, (void*)&sc0, (void*)&sc1,
        (void*)&WtEh, (void*)&WtEl, (void*)&WtDh, (void*)&WtDl,
        (void*)&AEh, (void*)&AEl, (void*)&ADh, (void*)&ADl,
        (void*)&out
    };
    hipLaunchCooperativeKernel((const void*)fused_kernel,
                               dim3(GRID_), dim3(256), args, 0, stream);
}

// Round 8
// 41.995 us; speedup vs baseline: 5.7709x; 5.7709x over previous
//
#include <hip/hip_runtime.h>
#include <hip/hip_bf16.h>

#define B_ 4
#define T_ 800
#define U_ 150
#define D_ 512
#define H_ 256
#define PADH2 132   // 132 % 32 == 4 -> worst LDS aliasing 2-way (free)

static constexpr float ARG_SCALE = 2.8853900817779268f; // 2/ln2: tanh(x)=1-2/(1+2^(c*x))
static constexpr float LOG2E_F   = 1.4426950408889634f;

typedef __attribute__((ext_vector_type(8))) short bf16x8;
typedef __attribute__((ext_vector_type(4))) float f32x4;

extern "C" __device__ float __ocml_exp2_f32(float);

__device__ __forceinline__ float fast_exp2(float x) {
#if __has_builtin(__builtin_amdgcn_exp2f)
    return __builtin_amdgcn_exp2f(x);
#else
    return __ocml_exp2_f32(x);
#endif
}
__device__ __forceinline__ float fast_rcp(float x) {
#if __has_builtin(__builtin_amdgcn_rcpf)
    return __builtin_amdgcn_rcpf(x);
#else
    return 1.0f / x;
#endif
}

// round-to-nearest-even fp32 -> bf16 hi, residual lo
__device__ __forceinline__ void bf16split(float x, unsigned short& hi, unsigned short& lo) {
    unsigned u = __builtin_bit_cast(unsigned, x);
    unsigned r = (u + 0x7FFFu + ((u >> 16) & 1u)) >> 16;
    hi = (unsigned short)r;
    float fh = __builtin_bit_cast(float, r << 16);
    float d = x - fh;
    unsigned u2 = __builtin_bit_cast(unsigned, d);
    unsigned r2 = (u2 + 0x7FFFu + ((u2 >> 16) & 1u)) >> 16;
    lo = (unsigned short)r2;
}

// ---------------------------------------------------------------------------
// K0: convert c*W -> frag-ordered bf16 hi/lo AND enc/dec -> frag-ordered A
// hi/lo chunks. Grid 952 x 256 = 243,712 threads = exactly one 16B A-chunk
// per thread; W conversion grid-strided on top (262,144 elems, <=2 iters).
// A frag layout: idx = ((chunk*16 + s)*64 + l)*8, l = q*16 + (row&15),
//   covering e = s*32 + q*8 .. +8  (gather: 32B contiguous read per thread).
// W frag layout: idx = (s*16+g)*512 + l*8 + j  (as verified since R5).
// ---------------------------------------------------------------------------
__global__ __launch_bounds__(256) void conv_kernel(
    const float* __restrict__ enc, const float* __restrict__ dec,
    const float* __restrict__ W_enc, const float* __restrict__ W_dec,
    unsigned short* __restrict__ WtEh, unsigned short* __restrict__ WtEl,
    unsigned short* __restrict__ WtDh, unsigned short* __restrict__ WtDl,
    unsigned short* __restrict__ AEh, unsigned short* __restrict__ AEl,
    unsigned short* __restrict__ ADh, unsigned short* __restrict__ ADl)
{
    const int nthreads = 952 * 256;
    const int gtid = blockIdx.x * 256 + threadIdx.x;

    // ---- W conversion ----
    for (int i = gtid; i < 2 * D_ * H_; i += nthreads) {
        const int which = i >> 17;
        const int r = i & (D_ * H_ - 1);
        const int e = r >> 8, h = r & 255;
        const float x = ARG_SCALE * (which ? W_dec[r] : W_enc[r]);
        unsigned short hi, lo; bf16split(x, hi, lo);
        const int s = e >> 5, q = (e >> 3) & 3, j = e & 7;
        const int g = h >> 4, rr = h & 15, l = q * 16 + rr;
        const size_t idx = (size_t)(s * 16 + g) * 512 + l * 8 + j;
        if (which) { WtDh[idx] = hi; WtDl[idx] = lo; }
        else       { WtEh[idx] = hi; WtEl[idx] = lo; }
    }

    // ---- A conversion: one 16B chunk per thread ----
    {
        const int u = gtid;                  // 0..243711
        const int c = u >> 10;               // chunk 0..237
        const int rem = u & 1023;
        const int s = rem >> 6, l = rem & 63;
        const float* in; unsigned short *oh, *ol; int cl, rmax;
        if (c < 200) { in = enc; oh = AEh; ol = AEl; cl = c;       rmax = 3199; }
        else         { in = dec; oh = ADh; ol = ADl; cl = c - 200; rmax = 599; }
        int row = cl * 16 + (l & 15); if (row > rmax) row = rmax;
        const int e0 = s * 32 + (l >> 4) * 8;
        const float4 f0 = ((const float4*)(in + (size_t)row * D_ + e0))[0];
        const float4 f1 = ((const float4*)(in + (size_t)row * D_ + e0))[1];
        const float v[8] = {f0.x, f0.y, f0.z, f0.w, f1.x, f1.y, f1.z, f1.w};
        bf16x8 ah, al;
        #pragma unroll
        for (int j = 0; j < 8; ++j) {
            unsigned short hi, lo; bf16split(v[j], hi, lo);
            ah[j] = (short)hi; al[j] = (short)lo;
        }
        const size_t di = ((size_t)(cl * 16 + s) * 64 + l) * 8;
        *(bf16x8*)&oh[di] = ah;
        *(bf16x8*)&ol[di] = al;
    }
}

// ---------------------------------------------------------------------------
// K1: LDS-free MFMA projection + exp2. Grid 952:
//   blk 0..799 : enc -> chunk = blk>>2 (16 rows), hq = blk&3 (64-h quarter)
//   blk 800..951: dec likewise. Wave w owns h-group g = 4*hq+w (16 h).
// 48 MFMA per wave (hi/lo 3-pass), all operands from coalesced frag arrays.
// out[row,h] = exp2( acc + c*bias[h] )  (c folded into W by conv).
// ---------------------------------------------------------------------------
__global__ __launch_bounds__(256) void proj_mfma_kernel(
    const unsigned short* __restrict__ WtEh, const unsigned short* __restrict__ WtEl,
    const unsigned short* __restrict__ WtDh, const unsigned short* __restrict__ WtDl,
    const unsigned short* __restrict__ AEh, const unsigned short* __restrict__ AEl,
    const unsigned short* __restrict__ ADh, const unsigned short* __restrict__ ADl,
    const float* __restrict__ b_enc, const float* __restrict__ b_dec,
    float* __restrict__ Ee, float* __restrict__ Ed)
{
    const int tid = threadIdx.x;
    int blk = blockIdx.x;
    const unsigned short *Ah_, *Al_, *Wh_, *Wl_; const float* bias;
    float* outp; int rmax;
    if (blk < 800) { Ah_ = AEh; Al_ = AEl; Wh_ = WtEh; Wl_ = WtEl;
                     bias = b_enc; outp = Ee; rmax = 3199; }
    else { blk -= 800; Ah_ = ADh; Al_ = ADl; Wh_ = WtDh; Wl_ = WtDl;
           bias = b_dec; outp = Ed; rmax = 599; }
    const int cl = blk >> 2, hq = blk & 3;
    const int row0 = cl * 16;

    const int lane = tid & 63, w = tid >> 6;
    const int q = lane >> 4, r15 = lane & 15;
    const int g = 4 * hq + w;

    const unsigned short* ap_h = Ah_ + ((size_t)(cl * 16) * 64 + lane) * 8;
    const unsigned short* ap_l = Al_ + ((size_t)(cl * 16) * 64 + lane) * 8;
    const unsigned short* bp_h = Wh_ + (size_t)g * 512 + lane * 8;
    const unsigned short* bp_l = Wl_ + (size_t)g * 512 + lane * 8;

    f32x4 acc = {0.f, 0.f, 0.f, 0.f};
    #pragma unroll 4
    for (int s = 0; s < 16; ++s) {
        const bf16x8 ah = *(const bf16x8*)(ap_h + (size_t)s * 512);
        const bf16x8 al = *(const bf16x8*)(ap_l + (size_t)s * 512);
        const bf16x8 bh = *(const bf16x8*)(bp_h + (size_t)s * 8192);
        const bf16x8 bl = *(const bf16x8*)(bp_l + (size_t)s * 8192);
        acc = __builtin_amdgcn_mfma_f32_16x16x32_bf16(ah, bh, acc, 0, 0, 0);
        acc = __builtin_amdgcn_mfma_f32_16x16x32_bf16(ah, bl, acc, 0, 0, 0);
        acc = __builtin_amdgcn_mfma_f32_16x16x32_bf16(al, bh, acc, 0, 0, 0);
    }

    const int h = g * 16 + r15;
    const float bv = bias[h];
    #pragma unroll
    for (int reg = 0; reg < 4; ++reg) {
        const int trow = row0 + 4 * q + reg;
        if (trow <= rmax)
            outp[(size_t)trow * H_ + h] = fast_exp2(fmaf(ARG_SCALE, bv, acc[reg]));
    }
}

// ---------------------------------------------------------------------------
// K2 (unchanged from R6): partial scores, one rcp per 4 h-elements.
//   q_i = fma(Ee_i, Ed_i, 1); quad = (Nab*Dcd + Ncd*Dab)/(Dab*Dcd)
// 128 threads; 32t x 32u tile; thread owns 4t x 2u. Grid (ut|hs, tt, b).
// ---------------------------------------------------------------------------
__global__ __launch_bounds__(128) void score_kernel(
    const float* __restrict__ Ee, const float* __restrict__ Ed,
    const float* __restrict__ w_score,
    float* __restrict__ sc0, float* __restrict__ sc1)
{
    const int tid = threadIdx.x;
    const int ut = blockIdx.x % 5, hs = blockIdx.x / 5;
    const int tt = blockIdx.y, b = blockIdx.z;

    __shared__ float eld[32][PADH2];
    __shared__ float dld[32][PADH2];

    const int t0 = tt * 32, u0 = ut * 32;
    const int hoff = hs * 128;

    #pragma unroll
    for (int k = 0; k < 8; ++k) {
        int idx = tid + 128 * k;
        int row = idx >> 5;
        int f4  = idx & 31;
        *(float4*)&eld[row][4 * f4] =
            *(const float4*)(Ee + (size_t)(b * T_ + t0 + row) * H_ + hoff + 4 * f4);
        int du = u0 + row; if (du > U_ - 1) du = U_ - 1;
        *(float4*)&dld[row][4 * f4] =
            *(const float4*)(Ed + (size_t)(b * U_ + du) * H_ + hoff + 4 * f4);
    }
    __syncthreads();

    const int tx = tid & 15, ty = tid >> 4;
    const float* e0 = &eld[4 * ty + 0][0];
    const float* e1 = &eld[4 * ty + 1][0];
    const float* e2 = &eld[4 * ty + 2][0];
    const float* e3 = &eld[4 * ty + 3][0];
    const float* d0 = &dld[tx][0];
    const float* d1 = &dld[tx + 16][0];
    const float* wp = w_score + hoff;

    float a00 = 0.f, a01 = 0.f, a10 = 0.f, a11 = 0.f;
    float a20 = 0.f, a21 = 0.f, a30 = 0.f, a31 = 0.f;

#define SQUAD(EV, DV, A) { \
    float q0 = fmaf(EV.x, DV.x, 1.f); \
    float q1 = fmaf(EV.y, DV.y, 1.f); \
    float q2 = fmaf(EV.z, DV.z, 1.f); \
    float q3 = fmaf(EV.w, DV.w, 1.f); \
    float Dab = q0 * q1, Dcd = q2 * q3; \
    float Nab = fmaf(w.x, q1, w.y * q0); \
    float Ncd = fmaf(w.z, q3, w.w * q2); \
    float N = fmaf(Nab, Dcd, Ncd * Dab); \
    A = fmaf(N, fast_rcp(Dab * Dcd), A); }

    #pragma unroll 4
    for (int h4 = 0; h4 < 32; ++h4) {
        const float4 w  = ((const float4*)wp)[h4];
        const float4 ea = *(const float4*)(e0 + 4 * h4);
        const float4 eb = *(const float4*)(e1 + 4 * h4);
        const float4 ec = *(const float4*)(e2 + 4 * h4);
        const float4 ed = *(const float4*)(e3 + 4 * h4);
        const float4 da = *(const float4*)(d0 + 4 * h4);
        const float4 db = *(const float4*)(d1 + 4 * h4);
        SQUAD(ea, da, a00) SQUAD(ea, db, a01)
        SQUAD(eb, da, a10) SQUAD(eb, db, a11)
        SQUAD(ec, da, a20) SQUAD(ec, db, a21)
        SQUAD(ed, da, a30) SQUAD(ed, db, a31)
    }
#undef SQUAD

    const float s0[4] = {a00, a10, a20, a30};
    const float s1[4] = {a01, a11, a21, a31};

    float* sout = hs ? sc1 : sc0;
    const int ua = u0 + tx, ub = ua + 16;
    #pragma unroll
    for (int j = 0; j < 4; ++j) {
        const int t = t0 + 4 * ty + j;
        const size_t base = (size_t)(b * T_ + t) * U_;
        sout[base + ua] = s0[j];
        if (ub < U_) sout[base + ub] = s1[j];
    }
}

// ---------------------------------------------------------------------------
// K3 (unchanged): softmax over U=150 of z = -2*(sc0+sc1). One wave per row.
// ---------------------------------------------------------------------------
__global__ __launch_bounds__(256) void softmax_kernel(
    const float* __restrict__ sc0, const float* __restrict__ sc1,
    float* __restrict__ out)
{
    const int tid  = threadIdx.x;
    const int wave = tid >> 6, lane = tid & 63;
    const int row  = blockIdx.x * 4 + wave;
    const size_t base = (size_t)row * U_;

    float z0 = -2.f * (sc0[base + lane]      + sc1[base + lane]);
    float z1 = -2.f * (sc0[base + lane + 64] + sc1[base + lane + 64]);
    const bool v2 = (lane + 128) < U_;
    float z2 = v2 ? -2.f * (sc0[base + lane + 128] + sc1[base + lane + 128])
                  : -INFINITY;

    float m = fmaxf(fmaxf(z0, z1), z2);
    #pragma unroll
    for (int off = 32; off > 0; off >>= 1) m = fmaxf(m, __shfl_xor(m, off));

    float p0 = fast_exp2((z0 - m) * LOG2E_F);
    float p1 = fast_exp2((z1 - m) * LOG2E_F);
    float p2 = v2 ? fast_exp2((z2 - m) * LOG2E_F) : 0.f;

    float s = p0 + p1 + p2;
    #pragma unroll
    for (int off = 32; off > 0; off >>= 1) s += __shfl_xor(s, off);

    const float inv = 1.0f / s;
    out[base + lane]      = p0 * inv;
    out[base + lane + 64] = p1 * inv;
    if (v2) out[base + lane + 128] = p2 * inv;
}

// ---------------------------------------------------------------------------
extern "C" void kernel_launch(void* const* d_in, const int* in_sizes, int n_in,
                              void* d_out, int out_size, void* d_ws, size_t ws_size,
                              hipStream_t stream) {
    const float* enc     = (const float*)d_in[0];
    const float* dec     = (const float*)d_in[1];
    const float* W_enc   = (const float*)d_in[2];
    const float* b_enc   = (const float*)d_in[3];
    const float* W_dec   = (const float*)d_in[4];
    const float* b_dec   = (const float*)d_in[5];
    const float* w_score = (const float*)d_in[6];
    // d_in[7] = b_score: cancels in softmax, unused.

    float* ws  = (float*)d_ws;
    float* Ee  = ws;                    // [3200,256]
    float* Ed  = Ee + 819200;           // [600,256]
    float* sc0 = Ed + 153600;           // [3200,150]
    float* sc1 = sc0 + 480000;          // [3200,150]
    unsigned short* WtEh = (unsigned short*)(sc1 + 480000);
    unsigned short* WtEl = WtEh + 131072;
    unsigned short* WtDh = WtEl + 131072;
    unsigned short* WtDl = WtDh + 131072;
    unsigned short* AEh  = WtDl + 131072;   // 200*16*64*8 = 1,638,400
    unsigned short* AEl  = AEh + 1638400;
    unsigned short* ADh  = AEl + 1638400;   // 38*16*64*8 = 311,296
    unsigned short* ADl  = ADh + 311296;
    float* out = (float*)d_out;

    conv_kernel<<<952, 256, 0, stream>>>(enc, dec, W_enc, W_dec,
                                         WtEh, WtEl, WtDh, WtDl,
                                         AEh, AEl, ADh, ADl);
    proj_mfma_kernel<<<952, 256, 0, stream>>>(WtEh, WtEl, WtDh, WtDl,
                                              AEh, AEl, ADh, ADl,
                                              b_enc, b_dec, Ee, Ed);
    score_kernel<<<dim3(10, 25, 4), 128, 0, stream>>>(Ee, Ed, w_score, sc0, sc1);
    softmax_kernel<<<800, 256, 0, stream>>>(sc0, sc1, out);
}